// Round 1
// baseline (714.766 us; speedup 1.0000x reference)
//
#include <hip/hip_runtime.h>
#include <math.h>

// ---------------------------------------------------------------------------
// DMoN pooling, edge-list formulation (dense adj never materialized).
// Pipeline:
//   1. weighted in-degree + CSR-by-dst build (count/scan/scatter)
//   2. GCN layer 1: ht = x@W1 ; h = relu(aggregate(ht) + b1)
//   3. GCN layer 2: ht = h@W2 ; h = relu(aggregate(ht) + b2)
//   4. s = softmax(h@Wp + bp) -> d_out ; cluster_size accumulation
//   5. per-edge reduction: tr(S^T A S), ca = A^T-weighted s sums, sum(ew)
//   6. finalize 3 scalars
// ---------------------------------------------------------------------------

// edge_index declared int64 in the reference, but JAX without x64 keeps int32.
// Detect on device: int64 little-endian small ids => odd 32-bit words are 0.
__device__ __forceinline__ bool ei_is_i64(const int* __restrict__ ei) {
  return ((ei[1] | ei[3] | ei[5] | ei[7]) == 0);
}
__device__ __forceinline__ int ld_idx(const int* __restrict__ ei, int pos, bool i64) {
  return i64 ? ei[2 * pos] : ei[pos];
}

__global__ __launch_bounds__(256) void edge_count(const int* __restrict__ ei,
                                                  const float* __restrict__ ew,
                                                  int* __restrict__ cnt,
                                                  float* __restrict__ deg, int E) {
  int e = blockIdx.x * 256 + threadIdx.x;
  if (e >= E) return;
  bool i64 = ei_is_i64(ei);
  int d = ld_idx(ei, E + e, i64);
  atomicAdd(&cnt[d], 1);
  atomicAdd(&deg[d], ew[e]);
}

__global__ __launch_bounds__(256) void compute_dis(const float* __restrict__ deg,
                                                   float* __restrict__ dis, int N) {
  int i = blockIdx.x * 256 + threadIdx.x;
  if (i < N) dis[i] = 1.0f / sqrtf(deg[i] + 1.0f);  // +1 = self-loop weight
}

__global__ __launch_bounds__(1024) void scan_kernel(const int* __restrict__ cnt,
                                                    int* __restrict__ rowptr, int n) {
  __shared__ int sums[1024];
  int tid = threadIdx.x;
  int CH = (n + 1023) >> 10;
  int beg = tid * CH, end = min(beg + CH, n);
  int s = 0;
  for (int i = beg; i < end; ++i) s += cnt[i];
  sums[tid] = s;
  __syncthreads();
  for (int off = 1; off < 1024; off <<= 1) {
    int v = (tid >= off) ? sums[tid - off] : 0;
    __syncthreads();
    sums[tid] += v;
    __syncthreads();
  }
  int run = (tid == 0) ? 0 : sums[tid - 1];
  for (int i = beg; i < end; ++i) { rowptr[i] = run; run += cnt[i]; }
  if (tid == 1023) rowptr[n] = run;
}

__global__ __launch_bounds__(256) void scatter_edges(const int* __restrict__ ei,
                                                     const float* __restrict__ ew,
                                                     const int* __restrict__ rowptr,
                                                     int* __restrict__ cur,
                                                     const float* __restrict__ dis,
                                                     int* __restrict__ col,
                                                     float* __restrict__ coef, int E) {
  int e = blockIdx.x * 256 + threadIdx.x;
  if (e >= E) return;
  bool i64 = ei_is_i64(ei);
  int s = ld_idx(ei, e, i64);
  int d = ld_idx(ei, E + e, i64);
  int p = rowptr[d] + atomicAdd(&cur[d], 1);
  col[p] = s;
  coef[p] = dis[s] * ew[e] * dis[d];
}

// C[M,N] = A[M,K] @ B[K,N]; 64x64 tile, 256 threads, 4x4 microtile, fp32.
__global__ __launch_bounds__(256) void gemm_f32(const float* __restrict__ A,
                                                const float* __restrict__ B,
                                                float* __restrict__ C,
                                                int M, int K, int N) {
  __shared__ float As[64][33];  // [m][k], pad to break bank conflicts
  __shared__ float Bs[32][64];  // [k][n]
  int tid = threadIdx.x;
  int tx = tid & 15, ty = tid >> 4;
  int row0 = blockIdx.x * 64, col0 = blockIdx.y * 64;
  float acc[4][4] = {};
  for (int k0 = 0; k0 < K; k0 += 32) {
#pragma unroll
    for (int r = 0; r < 2; ++r) {
      int lin = (tid + r * 256) * 4;  // 0..2047
      int ar = lin >> 5, ak = lin & 31;
      float4 av = make_float4(0.f, 0.f, 0.f, 0.f);
      int grow = row0 + ar;
      if (grow < M) av = *reinterpret_cast<const float4*>(&A[(size_t)grow * K + k0 + ak]);
      As[ar][ak + 0] = av.x; As[ar][ak + 1] = av.y;
      As[ar][ak + 2] = av.z; As[ar][ak + 3] = av.w;
      int bk = lin >> 6, bn = lin & 63;
      float4 bv = *reinterpret_cast<const float4*>(&B[(size_t)(k0 + bk) * N + col0 + bn]);
      *reinterpret_cast<float4*>(&Bs[bk][bn]) = bv;
    }
    __syncthreads();
#pragma unroll
    for (int k = 0; k < 32; ++k) {
      float a[4];
#pragma unroll
      for (int i = 0; i < 4; ++i) a[i] = As[ty * 4 + i][k];
      float4 bv = *reinterpret_cast<const float4*>(&Bs[k][tx * 4]);
      float b[4] = {bv.x, bv.y, bv.z, bv.w};
#pragma unroll
      for (int i = 0; i < 4; ++i)
#pragma unroll
        for (int j = 0; j < 4; ++j) acc[i][j] += a[i] * b[j];
    }
    __syncthreads();
  }
#pragma unroll
  for (int i = 0; i < 4; ++i) {
    int gr = row0 + ty * 4 + i;
    if (gr < M) {
      float4 o = make_float4(acc[i][0], acc[i][1], acc[i][2], acc[i][3]);
      *reinterpret_cast<float4*>(&C[(size_t)gr * N + col0 + tx * 4]) = o;
    }
  }
}

// One block (256 threads) per node: channel c accumulated over CSR row.
__global__ __launch_bounds__(256) void aggregate(const float* __restrict__ ht,
                                                 const int* __restrict__ rowptr,
                                                 const int* __restrict__ col,
                                                 const float* __restrict__ coef,
                                                 const float* __restrict__ dis,
                                                 const float* __restrict__ bias,
                                                 float* __restrict__ out, int N) {
  int i = blockIdx.x;
  int c = threadIdx.x;
  float d = dis[i];
  float acc = bias[c] + d * d * ht[(size_t)i * 256 + c];
  int e0 = rowptr[i], e1 = rowptr[i + 1];
  for (int p = e0; p < e1; ++p) {
    acc += coef[p] * ht[(size_t)col[p] * 256 + c];
  }
  out[(size_t)i * 256 + c] = fmaxf(acc, 0.0f);
}

// Pooling: lane = (group g, cluster k); wave handles 4 nodes. Softmax over 16
// via intra-group shuffles; writes s coalesced; accumulates cluster_size.
__global__ __launch_bounds__(256) void pool_kernel(const float* __restrict__ h,
                                                   const float* __restrict__ Wp,
                                                   const float* __restrict__ bp,
                                                   float* __restrict__ s_out,
                                                   float* __restrict__ cs_glob, int N) {
  __shared__ float Wps[256 * 16];  // natural [c][k] layout: conflict-free reads
  __shared__ float cs_loc[16];
  int tid = threadIdx.x;
  for (int idx = tid; idx < 4096; idx += 256) Wps[idx] = Wp[idx];
  if (tid < 16) cs_loc[tid] = 0.f;
  __syncthreads();
  int lane = tid & 63;
  int wave = tid >> 6;
  int k = lane & 15, g = lane >> 4;
  int node = blockIdx.x * 16 + wave * 4 + g;
  float acc = 0.f;
  if (node < N) {
    const float4* hrow = reinterpret_cast<const float4*>(h + (size_t)node * 256);
#pragma unroll 8
    for (int c4 = 0; c4 < 64; ++c4) {
      float4 hv = hrow[c4];
      int cb = c4 * 4;
      acc += hv.x * Wps[(cb + 0) * 16 + k];
      acc += hv.y * Wps[(cb + 1) * 16 + k];
      acc += hv.z * Wps[(cb + 2) * 16 + k];
      acc += hv.w * Wps[(cb + 3) * 16 + k];
    }
    acc += bp[k];
  }
  float mx = acc;
#pragma unroll
  for (int off = 1; off < 16; off <<= 1) mx = fmaxf(mx, __shfl_xor(mx, off));
  float ex = (node < N) ? expf(acc - mx) : 0.f;
  float sm = ex;
#pragma unroll
  for (int off = 1; off < 16; off <<= 1) sm += __shfl_xor(sm, off);
  float sval = (node < N) ? ex / sm : 0.f;
  if (node < N) s_out[(size_t)node * 16 + k] = sval;
  float v = sval;
  v += __shfl_xor(v, 16);
  v += __shfl_xor(v, 32);
  if (lane < 16) atomicAdd(&cs_loc[lane], v);
  __syncthreads();
  if (tid < 16) atomicAdd(&cs_glob[tid], cs_loc[tid]);
}

// Per-edge: tr += w*dot(s_src,s_dst); ca[k] += w*s_src[k]; sumw += w.
__global__ __launch_bounds__(256) void edge_reduce(const int* __restrict__ ei,
                                                   const float* __restrict__ ew,
                                                   const float* __restrict__ s,
                                                   float* __restrict__ scal, int E) {
  int e = blockIdx.x * 256 + threadIdx.x;
  float w = 0.f, dot = 0.f;
  float ca[16];
#pragma unroll
  for (int k = 0; k < 16; ++k) ca[k] = 0.f;
  if (e < E) {
    bool i64 = ei_is_i64(ei);
    int a = ld_idx(ei, e, i64);
    int b = ld_idx(ei, E + e, i64);
    w = ew[e];
    const float4* sa = reinterpret_cast<const float4*>(s + (size_t)a * 16);
    const float4* sb = reinterpret_cast<const float4*>(s + (size_t)b * 16);
#pragma unroll
    for (int q = 0; q < 4; ++q) {
      float4 av = sa[q], bv = sb[q];
      dot += av.x * bv.x + av.y * bv.y + av.z * bv.z + av.w * bv.w;
      ca[q * 4 + 0] = w * av.x; ca[q * 4 + 1] = w * av.y;
      ca[q * 4 + 2] = w * av.z; ca[q * 4 + 3] = w * av.w;
    }
    dot *= w;
  }
#pragma unroll
  for (int off = 32; off; off >>= 1) {
    dot += __shfl_xor(dot, off);
    w += __shfl_xor(w, off);
#pragma unroll
    for (int k = 0; k < 16; ++k) ca[k] += __shfl_xor(ca[k], off);
  }
  if ((threadIdx.x & 63) == 0) {
    atomicAdd(&scal[0], dot);
    atomicAdd(&scal[1], w);
#pragma unroll
    for (int k = 0; k < 16; ++k) atomicAdd(&scal[2 + k], ca[k]);
  }
}

__global__ void finalize(const float* __restrict__ scal, float* __restrict__ out,
                         int N, int s_elems) {
  if (threadIdx.x == 0 && blockIdx.x == 0) {
    float tr = scal[0], m2 = scal[1];  // m2 = 2m = sum(ew)
    float ca2 = 0.f, cs2 = 0.f;
    for (int k = 0; k < 16; ++k) {
      ca2 += scal[2 + k] * scal[2 + k];
      cs2 += scal[18 + k] * scal[18 + k];
    }
    float sp = -(tr - ca2 / m2) / m2;
    float cl = sqrtf(cs2) / (float)N * 4.0f - 1.0f;  // sqrt(K)=4
    out[s_elems + 0] = 100.f * (sp + cl);
    out[s_elems + 1] = 100.f * sp;
    out[s_elems + 2] = 100.f * cl;
  }
}

extern "C" void kernel_launch(void* const* d_in, const int* in_sizes, int n_in,
                              void* d_out, int out_size, void* d_ws, size_t ws_size,
                              hipStream_t stream) {
  const float* x  = (const float*)d_in[0];
  const int*   ei = (const int*)d_in[1];   // int32 or int64 (device-detected)
  const float* ew = (const float*)d_in[2];
  const float* W1 = (const float*)d_in[3];
  const float* b1 = (const float*)d_in[4];
  const float* W2 = (const float*)d_in[5];
  const float* b2 = (const float*)d_in[6];
  const float* Wp = (const float*)d_in[7];
  const float* bp = (const float*)d_in[8];
  float* out = (float*)d_out;

  const int IN_C = 128, HID = 256;
  const int N = in_sizes[0] / IN_C;   // 10000
  const int E = in_sizes[2];          // 160000

  // workspace carve (aligned 256B)
  char* p = (char*)d_ws;
  auto alloc = [&](size_t b) { char* r = p; p += (b + 255) & ~(size_t)255; return r; };
  float* ht     = (float*)alloc((size_t)N * HID * 4);
  float* h      = (float*)alloc((size_t)N * HID * 4);
  float* deg    = (float*)alloc((size_t)N * 4);
  float* dis    = (float*)alloc((size_t)N * 4);
  int*   cnt    = (int*)alloc((size_t)N * 4);
  int*   cur    = (int*)alloc((size_t)N * 4);
  int*   rowptr = (int*)alloc((size_t)(N + 1) * 4);
  int*   col    = (int*)alloc((size_t)E * 4);
  float* coef   = (float*)alloc((size_t)E * 4);
  float* scal   = (float*)alloc(64 * 4);  // [0]=tr [1]=sumw [2..17]=ca [18..33]=cs
  if ((size_t)(p - (char*)d_ws) > ws_size) return;  // fail loudly via poison

  hipMemsetAsync(deg, 0, (size_t)N * 4, stream);
  hipMemsetAsync(cnt, 0, (size_t)N * 4, stream);
  hipMemsetAsync(cur, 0, (size_t)N * 4, stream);
  hipMemsetAsync(scal, 0, 64 * 4, stream);

  int eb = (E + 255) / 256;
  edge_count<<<eb, 256, 0, stream>>>(ei, ew, cnt, deg, E);
  compute_dis<<<(N + 255) / 256, 256, 0, stream>>>(deg, dis, N);
  scan_kernel<<<1, 1024, 0, stream>>>(cnt, rowptr, N);
  scatter_edges<<<eb, 256, 0, stream>>>(ei, ew, rowptr, cur, dis, col, coef, E);

  dim3 gg((N + 63) / 64, HID / 64);
  gemm_f32<<<gg, 256, 0, stream>>>(x, W1, ht, N, IN_C, HID);
  aggregate<<<N, 256, 0, stream>>>(ht, rowptr, col, coef, dis, b1, h, N);
  gemm_f32<<<gg, 256, 0, stream>>>(h, W2, ht, N, HID, HID);
  aggregate<<<N, 256, 0, stream>>>(ht, rowptr, col, coef, dis, b2, h, N);

  pool_kernel<<<(N + 15) / 16, 256, 0, stream>>>(h, Wp, bp, out, scal + 18, N);
  edge_reduce<<<eb, 256, 0, stream>>>(ei, ew, out, scal, E);
  finalize<<<1, 64, 0, stream>>>(scal, out, N, N * 16);
}

// Round 2
// 208.320 us; speedup vs baseline: 3.4311x; 3.4311x over previous
//
#include <hip/hip_runtime.h>
#include <math.h>

// ---------------------------------------------------------------------------
// DMoN pooling, edge-list formulation (dense adj never materialized).
//   1. weighted in-degree + CSR-by-dst build (count/scan/scatter)
//   2. GCN layer 1: ht = x@W1 ; h = relu(aggregate(ht) + b1)
//   3. GCN layer 2: ht = h@W2 ; h = relu(aggregate(ht) + b2)
//   4. s = softmax(h@Wp + bp) -> d_out ; per-block cluster-size partials
//   5. per-edge reduction -> per-block partials (NO global atomics)
//   6. finalize: reduce partials, emit 3 scalars
// ---------------------------------------------------------------------------

#define ER_BLOCKS 128  // edge_reduce grid; partials buffer sized to match

// edge_index declared int64 in the reference, but JAX without x64 keeps int32.
// Detect on device: int64 little-endian small ids => odd 32-bit words are 0.
__device__ __forceinline__ bool ei_is_i64(const int* __restrict__ ei) {
  return ((ei[1] | ei[3] | ei[5] | ei[7]) == 0);
}
__device__ __forceinline__ int ld_idx(const int* __restrict__ ei, int pos, bool i64) {
  return i64 ? ei[2 * pos] : ei[pos];
}

__global__ __launch_bounds__(256) void edge_count(const int* __restrict__ ei,
                                                  const float* __restrict__ ew,
                                                  int* __restrict__ cnt,
                                                  float* __restrict__ deg, int E) {
  int e = blockIdx.x * 256 + threadIdx.x;
  if (e >= E) return;
  bool i64 = ei_is_i64(ei);
  int d = ld_idx(ei, E + e, i64);
  atomicAdd(&cnt[d], 1);
  atomicAdd(&deg[d], ew[e]);
}

__global__ __launch_bounds__(256) void compute_dis(const float* __restrict__ deg,
                                                   float* __restrict__ dis, int N) {
  int i = blockIdx.x * 256 + threadIdx.x;
  if (i < N) dis[i] = 1.0f / sqrtf(deg[i] + 1.0f);  // +1 = self-loop weight
}

__global__ __launch_bounds__(1024) void scan_kernel(const int* __restrict__ cnt,
                                                    int* __restrict__ rowptr, int n) {
  __shared__ int sums[1024];
  int tid = threadIdx.x;
  int CH = (n + 1023) >> 10;
  int beg = tid * CH, end = min(beg + CH, n);
  int s = 0;
  for (int i = beg; i < end; ++i) s += cnt[i];
  sums[tid] = s;
  __syncthreads();
  for (int off = 1; off < 1024; off <<= 1) {
    int v = (tid >= off) ? sums[tid - off] : 0;
    __syncthreads();
    sums[tid] += v;
    __syncthreads();
  }
  int run = (tid == 0) ? 0 : sums[tid - 1];
  for (int i = beg; i < end; ++i) { rowptr[i] = run; run += cnt[i]; }
  if (tid == 1023) rowptr[n] = run;
}

__global__ __launch_bounds__(256) void scatter_edges(const int* __restrict__ ei,
                                                     const float* __restrict__ ew,
                                                     const int* __restrict__ rowptr,
                                                     int* __restrict__ cur,
                                                     const float* __restrict__ dis,
                                                     int* __restrict__ col,
                                                     float* __restrict__ coef, int E) {
  int e = blockIdx.x * 256 + threadIdx.x;
  if (e >= E) return;
  bool i64 = ei_is_i64(ei);
  int s = ld_idx(ei, e, i64);
  int d = ld_idx(ei, E + e, i64);
  int p = rowptr[d] + atomicAdd(&cur[d], 1);
  col[p] = s;
  coef[p] = dis[s] * ew[e] * dis[d];
}

// C[M,N] = A[M,K] @ B[K,N]; 64x64 tile, 256 threads, 4x4 microtile, fp32.
__global__ __launch_bounds__(256) void gemm_f32(const float* __restrict__ A,
                                                const float* __restrict__ B,
                                                float* __restrict__ C,
                                                int M, int K, int N) {
  __shared__ float As[64][33];  // [m][k], pad to break bank conflicts
  __shared__ float Bs[32][64];  // [k][n]
  int tid = threadIdx.x;
  int tx = tid & 15, ty = tid >> 4;
  int row0 = blockIdx.x * 64, col0 = blockIdx.y * 64;
  float acc[4][4] = {};
  for (int k0 = 0; k0 < K; k0 += 32) {
#pragma unroll
    for (int r = 0; r < 2; ++r) {
      int lin = (tid + r * 256) * 4;  // 0..2047
      int ar = lin >> 5, ak = lin & 31;
      float4 av = make_float4(0.f, 0.f, 0.f, 0.f);
      int grow = row0 + ar;
      if (grow < M) av = *reinterpret_cast<const float4*>(&A[(size_t)grow * K + k0 + ak]);
      As[ar][ak + 0] = av.x; As[ar][ak + 1] = av.y;
      As[ar][ak + 2] = av.z; As[ar][ak + 3] = av.w;
      int bk = lin >> 6, bn = lin & 63;
      float4 bv = *reinterpret_cast<const float4*>(&B[(size_t)(k0 + bk) * N + col0 + bn]);
      *reinterpret_cast<float4*>(&Bs[bk][bn]) = bv;
    }
    __syncthreads();
#pragma unroll
    for (int k = 0; k < 32; ++k) {
      float a[4];
#pragma unroll
      for (int i = 0; i < 4; ++i) a[i] = As[ty * 4 + i][k];
      float4 bv = *reinterpret_cast<const float4*>(&Bs[k][tx * 4]);
      float b[4] = {bv.x, bv.y, bv.z, bv.w};
#pragma unroll
      for (int i = 0; i < 4; ++i)
#pragma unroll
        for (int j = 0; j < 4; ++j) acc[i][j] += a[i] * b[j];
    }
    __syncthreads();
  }
#pragma unroll
  for (int i = 0; i < 4; ++i) {
    int gr = row0 + ty * 4 + i;
    if (gr < M) {
      float4 o = make_float4(acc[i][0], acc[i][1], acc[i][2], acc[i][3]);
      *reinterpret_cast<float4*>(&C[(size_t)gr * N + col0 + tx * 4]) = o;
    }
  }
}

// One block (256 threads) per node: channel c accumulated over CSR row.
__global__ __launch_bounds__(256) void aggregate(const float* __restrict__ ht,
                                                 const int* __restrict__ rowptr,
                                                 const int* __restrict__ col,
                                                 const float* __restrict__ coef,
                                                 const float* __restrict__ dis,
                                                 const float* __restrict__ bias,
                                                 float* __restrict__ out, int N) {
  int i = blockIdx.x;
  int c = threadIdx.x;
  float d = dis[i];
  float acc = bias[c] + d * d * ht[(size_t)i * 256 + c];
  int e0 = rowptr[i], e1 = rowptr[i + 1];
  for (int p = e0; p < e1; ++p) {
    acc += coef[p] * ht[(size_t)col[p] * 256 + c];
  }
  out[(size_t)i * 256 + c] = fmaxf(acc, 0.0f);
}

// Pooling: lane = (group g, cluster k); wave handles 4 nodes. Softmax over 16
// via intra-group shuffles; writes s coalesced; per-block cluster-size
// partials to a PRIVATE workspace slot (no global atomics).
__global__ __launch_bounds__(256) void pool_kernel(const float* __restrict__ h,
                                                   const float* __restrict__ Wp,
                                                   const float* __restrict__ bp,
                                                   float* __restrict__ s_out,
                                                   float* __restrict__ cs_part, int N) {
  __shared__ float Wps[256 * 16];  // natural [c][k] layout: conflict-free reads
  __shared__ float cs_loc[16];
  int tid = threadIdx.x;
  for (int idx = tid; idx < 4096; idx += 256) Wps[idx] = Wp[idx];
  if (tid < 16) cs_loc[tid] = 0.f;
  __syncthreads();
  int lane = tid & 63;
  int wave = tid >> 6;
  int k = lane & 15, g = lane >> 4;
  int node = blockIdx.x * 16 + wave * 4 + g;
  float acc = 0.f;
  if (node < N) {
    const float4* hrow = reinterpret_cast<const float4*>(h + (size_t)node * 256);
#pragma unroll 8
    for (int c4 = 0; c4 < 64; ++c4) {
      float4 hv = hrow[c4];
      int cb = c4 * 4;
      acc += hv.x * Wps[(cb + 0) * 16 + k];
      acc += hv.y * Wps[(cb + 1) * 16 + k];
      acc += hv.z * Wps[(cb + 2) * 16 + k];
      acc += hv.w * Wps[(cb + 3) * 16 + k];
    }
    acc += bp[k];
  }
  float mx = acc;
#pragma unroll
  for (int off = 1; off < 16; off <<= 1) mx = fmaxf(mx, __shfl_xor(mx, off));
  float ex = (node < N) ? expf(acc - mx) : 0.f;
  float sm = ex;
#pragma unroll
  for (int off = 1; off < 16; off <<= 1) sm += __shfl_xor(sm, off);
  float sval = (node < N) ? ex / sm : 0.f;
  if (node < N) s_out[(size_t)node * 16 + k] = sval;
  float v = sval;
  v += __shfl_xor(v, 16);
  v += __shfl_xor(v, 32);
  if (lane < 16) atomicAdd(&cs_loc[lane], v);  // LDS atomic: cheap
  __syncthreads();
  if (tid < 16) cs_part[(size_t)blockIdx.x * 16 + tid] = cs_loc[tid];
}

// Per-edge: dot += w*dot(s_src,s_dst); ca[k] += w*s_src[k]; sumw += w.
// Grid-stride over ER_BLOCKS blocks; per-block partials (no global atomics).
__global__ __launch_bounds__(256) void edge_reduce(const int* __restrict__ ei,
                                                   const float* __restrict__ ew,
                                                   const float* __restrict__ s,
                                                   float* __restrict__ part, int E) {
  __shared__ float loc[18];
  int tid = threadIdx.x;
  if (tid < 18) loc[tid] = 0.f;
  __syncthreads();
  bool i64 = ei_is_i64(ei);
  float dot = 0.f, w = 0.f;
  float ca[16];
#pragma unroll
  for (int k = 0; k < 16; ++k) ca[k] = 0.f;
  for (int e = blockIdx.x * 256 + tid; e < E; e += gridDim.x * 256) {
    int a = ld_idx(ei, e, i64);
    int b = ld_idx(ei, E + e, i64);
    float we = ew[e];
    const float4* sa = reinterpret_cast<const float4*>(s + (size_t)a * 16);
    const float4* sb = reinterpret_cast<const float4*>(s + (size_t)b * 16);
    float d = 0.f;
#pragma unroll
    for (int q = 0; q < 4; ++q) {
      float4 av = sa[q], bv = sb[q];
      d += av.x * bv.x + av.y * bv.y + av.z * bv.z + av.w * bv.w;
      ca[q * 4 + 0] += we * av.x; ca[q * 4 + 1] += we * av.y;
      ca[q * 4 + 2] += we * av.z; ca[q * 4 + 3] += we * av.w;
    }
    dot += we * d;
    w += we;
  }
#pragma unroll
  for (int off = 32; off; off >>= 1) {
    dot += __shfl_xor(dot, off);
    w += __shfl_xor(w, off);
#pragma unroll
    for (int k = 0; k < 16; ++k) ca[k] += __shfl_xor(ca[k], off);
  }
  if ((tid & 63) == 0) {  // lane 0 of each wave: LDS atomics (4 waves x 18)
    atomicAdd(&loc[0], dot);
    atomicAdd(&loc[1], w);
#pragma unroll
    for (int k = 0; k < 16; ++k) atomicAdd(&loc[2 + k], ca[k]);
  }
  __syncthreads();
  if (tid < 18) part[(size_t)blockIdx.x * 18 + tid] = loc[tid];
}

// Single block: reduce edge partials (ER_BLOCKS x 18) + cs partials (PB x 16),
// compute the 3 scalar losses.
__global__ __launch_bounds__(256) void finalize(const float* __restrict__ epart,
                                                const float* __restrict__ cs_part,
                                                int pool_blocks,
                                                float* __restrict__ out,
                                                int N, int s_elems) {
  __shared__ float red[18];
  __shared__ float csl[256];
  __shared__ float cs[16];
  int tid = threadIdx.x;
  if (tid < 18) {
    float a = 0.f;
    for (int b = 0; b < ER_BLOCKS; ++b) a += epart[(size_t)b * 18 + tid];
    red[tid] = a;
  }
  {  // cs: col = tid&15, slice = tid>>4 (16 slices over pool_blocks)
    int k = tid & 15, sl = tid >> 4;
    float a = 0.f;
    for (int b = sl; b < pool_blocks; b += 16) a += cs_part[(size_t)b * 16 + k];
    csl[tid] = a;
  }
  __syncthreads();
  if (tid < 16) {
    float a = 0.f;
#pragma unroll
    for (int sl = 0; sl < 16; ++sl) a += csl[sl * 16 + tid];
    cs[tid] = a;
  }
  __syncthreads();
  if (tid == 0) {
    float tr = red[0], m2 = red[1];  // m2 = 2m = sum(ew)
    float ca2 = 0.f, cs2 = 0.f;
    for (int k = 0; k < 16; ++k) {
      ca2 += red[2 + k] * red[2 + k];
      cs2 += cs[k] * cs[k];
    }
    float sp = -(tr - ca2 / m2) / m2;
    float cl = sqrtf(cs2) / (float)N * 4.0f - 1.0f;  // sqrt(K)=4
    out[s_elems + 0] = 100.f * (sp + cl);
    out[s_elems + 1] = 100.f * sp;
    out[s_elems + 2] = 100.f * cl;
  }
}

extern "C" void kernel_launch(void* const* d_in, const int* in_sizes, int n_in,
                              void* d_out, int out_size, void* d_ws, size_t ws_size,
                              hipStream_t stream) {
  const float* x  = (const float*)d_in[0];
  const int*   ei = (const int*)d_in[1];   // int32 or int64 (device-detected)
  const float* ew = (const float*)d_in[2];
  const float* W1 = (const float*)d_in[3];
  const float* b1 = (const float*)d_in[4];
  const float* W2 = (const float*)d_in[5];
  const float* b2 = (const float*)d_in[6];
  const float* Wp = (const float*)d_in[7];
  const float* bp = (const float*)d_in[8];
  float* out = (float*)d_out;

  const int IN_C = 128, HID = 256;
  const int N = in_sizes[0] / IN_C;   // 10000
  const int E = in_sizes[2];          // 160000
  const int pool_blocks = (N + 15) / 16;

  // workspace carve (aligned 256B)
  char* p = (char*)d_ws;
  auto alloc = [&](size_t b) { char* r = p; p += (b + 255) & ~(size_t)255; return r; };
  float* ht      = (float*)alloc((size_t)N * HID * 4);
  float* h       = (float*)alloc((size_t)N * HID * 4);
  float* deg     = (float*)alloc((size_t)N * 4);
  float* dis     = (float*)alloc((size_t)N * 4);
  int*   cnt     = (int*)alloc((size_t)N * 4);
  int*   cur     = (int*)alloc((size_t)N * 4);
  int*   rowptr  = (int*)alloc((size_t)(N + 1) * 4);
  int*   col     = (int*)alloc((size_t)E * 4);
  float* coef    = (float*)alloc((size_t)E * 4);
  float* epart   = (float*)alloc((size_t)ER_BLOCKS * 18 * 4);
  float* cs_part = (float*)alloc((size_t)pool_blocks * 16 * 4);
  if ((size_t)(p - (char*)d_ws) > ws_size) return;  // fail loudly via poison

  hipMemsetAsync(deg, 0, (size_t)N * 4, stream);
  hipMemsetAsync(cnt, 0, (size_t)N * 4, stream);
  hipMemsetAsync(cur, 0, (size_t)N * 4, stream);

  int eb = (E + 255) / 256;
  edge_count<<<eb, 256, 0, stream>>>(ei, ew, cnt, deg, E);
  compute_dis<<<(N + 255) / 256, 256, 0, stream>>>(deg, dis, N);
  scan_kernel<<<1, 1024, 0, stream>>>(cnt, rowptr, N);
  scatter_edges<<<eb, 256, 0, stream>>>(ei, ew, rowptr, cur, dis, col, coef, E);

  dim3 gg((N + 63) / 64, HID / 64);
  gemm_f32<<<gg, 256, 0, stream>>>(x, W1, ht, N, IN_C, HID);
  aggregate<<<N, 256, 0, stream>>>(ht, rowptr, col, coef, dis, b1, h, N);
  gemm_f32<<<gg, 256, 0, stream>>>(h, W2, ht, N, HID, HID);
  aggregate<<<N, 256, 0, stream>>>(ht, rowptr, col, coef, dis, b2, h, N);

  pool_kernel<<<pool_blocks, 256, 0, stream>>>(h, Wp, bp, out, cs_part, N);
  edge_reduce<<<ER_BLOCKS, 256, 0, stream>>>(ei, ew, out, epart, E);
  finalize<<<1, 256, 0, stream>>>(epart, cs_part, pool_blocks, out, N, N * 16);
}

// Round 3
// 205.415 us; speedup vs baseline: 3.4796x; 1.0141x over previous
//
#include <hip/hip_runtime.h>
#include <math.h>

// ---------------------------------------------------------------------------
// DMoN pooling, edge-list formulation (dense adj never materialized).
//   0. zero_init: deg/cnt/cur (own kernel -- rocclr fill was 44us per call!)
//   1. weighted in-degree + CSR-by-dst build (count/scan+dis/scatter)
//   2. GCN layer 1: ht = x@W1 ; h = relu(aggregate(ht) + b1)
//   3. GCN layer 2: ht = h@W2 ; h = relu(aggregate(ht) + b2)
//   4. s = softmax(h@Wp + bp) -> d_out ; per-block cluster-size partials
//   5. per-edge reduction -> per-block partials (NO global atomics)
//   6. finalize: reduce partials, emit 3 scalars
// ---------------------------------------------------------------------------

#define ER_BLOCKS 128  // edge_reduce grid; partials buffer sized to match

// edge_index declared int64 in the reference, but JAX without x64 keeps int32.
// Detect on device: int64 little-endian small ids => odd 32-bit words are 0.
__device__ __forceinline__ bool ei_is_i64(const int* __restrict__ ei) {
  return ((ei[1] | ei[3] | ei[5] | ei[7]) == 0);
}
__device__ __forceinline__ int ld_idx(const int* __restrict__ ei, int pos, bool i64) {
  return i64 ? ei[2 * pos] : ei[pos];
}

__global__ __launch_bounds__(256) void zero_init(int4* __restrict__ p, int n4) {
  int i = blockIdx.x * 256 + threadIdx.x;
  if (i < n4) p[i] = make_int4(0, 0, 0, 0);
}

__global__ __launch_bounds__(256) void edge_count(const int* __restrict__ ei,
                                                  const float* __restrict__ ew,
                                                  int* __restrict__ cnt,
                                                  float* __restrict__ deg, int E) {
  int e = blockIdx.x * 256 + threadIdx.x;
  if (e >= E) return;
  bool i64 = ei_is_i64(ei);
  int d = ld_idx(ei, E + e, i64);
  atomicAdd(&cnt[d], 1);
  atomicAdd(&deg[d], ew[e]);
}

// Single block: chunked scan of cnt -> rowptr, plus dis = 1/sqrt(deg+1).
__global__ __launch_bounds__(1024) void scan_kernel(const int* __restrict__ cnt,
                                                    int* __restrict__ rowptr,
                                                    const float* __restrict__ deg,
                                                    float* __restrict__ dis, int n) {
  __shared__ int sums[1024];
  int tid = threadIdx.x;
  for (int i = tid; i < n; i += 1024) dis[i] = 1.0f / sqrtf(deg[i] + 1.0f);
  int CH = (n + 1023) >> 10;
  int beg = tid * CH, end = min(beg + CH, n);
  int s = 0;
  for (int i = beg; i < end; ++i) s += cnt[i];
  sums[tid] = s;
  __syncthreads();
  for (int off = 1; off < 1024; off <<= 1) {
    int v = (tid >= off) ? sums[tid - off] : 0;
    __syncthreads();
    sums[tid] += v;
    __syncthreads();
  }
  int run = (tid == 0) ? 0 : sums[tid - 1];
  for (int i = beg; i < end; ++i) { rowptr[i] = run; run += cnt[i]; }
  if (tid == 1023) rowptr[n] = run;
}

__global__ __launch_bounds__(256) void scatter_edges(const int* __restrict__ ei,
                                                     const float* __restrict__ ew,
                                                     const int* __restrict__ rowptr,
                                                     int* __restrict__ cur,
                                                     const float* __restrict__ dis,
                                                     int* __restrict__ col,
                                                     float* __restrict__ coef, int E) {
  int e = blockIdx.x * 256 + threadIdx.x;
  if (e >= E) return;
  bool i64 = ei_is_i64(ei);
  int s = ld_idx(ei, e, i64);
  int d = ld_idx(ei, E + e, i64);
  int p = rowptr[d] + atomicAdd(&cur[d], 1);
  col[p] = s;
  coef[p] = dis[s] * ew[e] * dis[d];
}

// C[M,N] = A[M,K] @ B[K,N]; 64x64 tile, 256 threads, 4x4 microtile, fp32.
__global__ __launch_bounds__(256) void gemm_f32(const float* __restrict__ A,
                                                const float* __restrict__ B,
                                                float* __restrict__ C,
                                                int M, int K, int N) {
  __shared__ float As[64][33];  // [m][k], pad to break bank conflicts
  __shared__ float Bs[32][64];  // [k][n]
  int tid = threadIdx.x;
  int tx = tid & 15, ty = tid >> 4;
  int row0 = blockIdx.x * 64, col0 = blockIdx.y * 64;
  float acc[4][4] = {};
  for (int k0 = 0; k0 < K; k0 += 32) {
#pragma unroll
    for (int r = 0; r < 2; ++r) {
      int lin = (tid + r * 256) * 4;  // 0..2047
      int ar = lin >> 5, ak = lin & 31;
      float4 av = make_float4(0.f, 0.f, 0.f, 0.f);
      int grow = row0 + ar;
      if (grow < M) av = *reinterpret_cast<const float4*>(&A[(size_t)grow * K + k0 + ak]);
      As[ar][ak + 0] = av.x; As[ar][ak + 1] = av.y;
      As[ar][ak + 2] = av.z; As[ar][ak + 3] = av.w;
      int bk = lin >> 6, bn = lin & 63;
      float4 bv = *reinterpret_cast<const float4*>(&B[(size_t)(k0 + bk) * N + col0 + bn]);
      *reinterpret_cast<float4*>(&Bs[bk][bn]) = bv;
    }
    __syncthreads();
#pragma unroll
    for (int k = 0; k < 32; ++k) {
      float a[4];
#pragma unroll
      for (int i = 0; i < 4; ++i) a[i] = As[ty * 4 + i][k];
      float4 bv = *reinterpret_cast<const float4*>(&Bs[k][tx * 4]);
      float b[4] = {bv.x, bv.y, bv.z, bv.w};
#pragma unroll
      for (int i = 0; i < 4; ++i)
#pragma unroll
        for (int j = 0; j < 4; ++j) acc[i][j] += a[i] * b[j];
    }
    __syncthreads();
  }
#pragma unroll
  for (int i = 0; i < 4; ++i) {
    int gr = row0 + ty * 4 + i;
    if (gr < M) {
      float4 o = make_float4(acc[i][0], acc[i][1], acc[i][2], acc[i][3]);
      *reinterpret_cast<float4*>(&C[(size_t)gr * N + col0 + tx * 4]) = o;
    }
  }
}

// One block (256 threads) per node: channel c accumulated over CSR row.
__global__ __launch_bounds__(256) void aggregate(const float* __restrict__ ht,
                                                 const int* __restrict__ rowptr,
                                                 const int* __restrict__ col,
                                                 const float* __restrict__ coef,
                                                 const float* __restrict__ dis,
                                                 const float* __restrict__ bias,
                                                 float* __restrict__ out, int N) {
  int i = blockIdx.x;
  int c = threadIdx.x;
  float d = dis[i];
  float acc = bias[c] + d * d * ht[(size_t)i * 256 + c];
  int e0 = rowptr[i], e1 = rowptr[i + 1];
  for (int p = e0; p < e1; ++p) {
    acc += coef[p] * ht[(size_t)col[p] * 256 + c];
  }
  out[(size_t)i * 256 + c] = fmaxf(acc, 0.0f);
}

// Pooling: lane = (group g, cluster k); wave handles 4 nodes. Softmax over 16
// via intra-group shuffles; writes s coalesced; per-block cluster-size
// partials to a PRIVATE workspace slot (no global atomics).
__global__ __launch_bounds__(256) void pool_kernel(const float* __restrict__ h,
                                                   const float* __restrict__ Wp,
                                                   const float* __restrict__ bp,
                                                   float* __restrict__ s_out,
                                                   float* __restrict__ cs_part, int N) {
  __shared__ float Wps[256 * 16];  // natural [c][k] layout: conflict-free reads
  __shared__ float cs_loc[16];
  int tid = threadIdx.x;
  for (int idx = tid; idx < 4096; idx += 256) Wps[idx] = Wp[idx];
  if (tid < 16) cs_loc[tid] = 0.f;
  __syncthreads();
  int lane = tid & 63;
  int wave = tid >> 6;
  int k = lane & 15, g = lane >> 4;
  int node = blockIdx.x * 16 + wave * 4 + g;
  float acc = 0.f;
  if (node < N) {
    const float4* hrow = reinterpret_cast<const float4*>(h + (size_t)node * 256);
#pragma unroll 8
    for (int c4 = 0; c4 < 64; ++c4) {
      float4 hv = hrow[c4];
      int cb = c4 * 4;
      acc += hv.x * Wps[(cb + 0) * 16 + k];
      acc += hv.y * Wps[(cb + 1) * 16 + k];
      acc += hv.z * Wps[(cb + 2) * 16 + k];
      acc += hv.w * Wps[(cb + 3) * 16 + k];
    }
    acc += bp[k];
  }
  float mx = acc;
#pragma unroll
  for (int off = 1; off < 16; off <<= 1) mx = fmaxf(mx, __shfl_xor(mx, off));
  float ex = (node < N) ? expf(acc - mx) : 0.f;
  float sm = ex;
#pragma unroll
  for (int off = 1; off < 16; off <<= 1) sm += __shfl_xor(sm, off);
  float sval = (node < N) ? ex / sm : 0.f;
  if (node < N) s_out[(size_t)node * 16 + k] = sval;
  float v = sval;
  v += __shfl_xor(v, 16);
  v += __shfl_xor(v, 32);
  if (lane < 16) atomicAdd(&cs_loc[lane], v);  // LDS atomic: cheap
  __syncthreads();
  if (tid < 16) cs_part[(size_t)blockIdx.x * 16 + tid] = cs_loc[tid];
}

// Per-edge: dot += w*dot(s_src,s_dst); ca[k] += w*s_src[k]; sumw += w.
// Grid-stride over ER_BLOCKS blocks; per-block partials (no global atomics).
__global__ __launch_bounds__(256) void edge_reduce(const int* __restrict__ ei,
                                                   const float* __restrict__ ew,
                                                   const float* __restrict__ s,
                                                   float* __restrict__ part, int E) {
  __shared__ float loc[18];
  int tid = threadIdx.x;
  if (tid < 18) loc[tid] = 0.f;
  __syncthreads();
  bool i64 = ei_is_i64(ei);
  float dot = 0.f, w = 0.f;
  float ca[16];
#pragma unroll
  for (int k = 0; k < 16; ++k) ca[k] = 0.f;
  for (int e = blockIdx.x * 256 + tid; e < E; e += gridDim.x * 256) {
    int a = ld_idx(ei, e, i64);
    int b = ld_idx(ei, E + e, i64);
    float we = ew[e];
    const float4* sa = reinterpret_cast<const float4*>(s + (size_t)a * 16);
    const float4* sb = reinterpret_cast<const float4*>(s + (size_t)b * 16);
    float d = 0.f;
#pragma unroll
    for (int q = 0; q < 4; ++q) {
      float4 av = sa[q], bv = sb[q];
      d += av.x * bv.x + av.y * bv.y + av.z * bv.z + av.w * bv.w;
      ca[q * 4 + 0] += we * av.x; ca[q * 4 + 1] += we * av.y;
      ca[q * 4 + 2] += we * av.z; ca[q * 4 + 3] += we * av.w;
    }
    dot += we * d;
    w += we;
  }
#pragma unroll
  for (int off = 32; off; off >>= 1) {
    dot += __shfl_xor(dot, off);
    w += __shfl_xor(w, off);
#pragma unroll
    for (int k = 0; k < 16; ++k) ca[k] += __shfl_xor(ca[k], off);
  }
  if ((tid & 63) == 0) {  // lane 0 of each wave: LDS atomics (4 waves x 18)
    atomicAdd(&loc[0], dot);
    atomicAdd(&loc[1], w);
#pragma unroll
    for (int k = 0; k < 16; ++k) atomicAdd(&loc[2 + k], ca[k]);
  }
  __syncthreads();
  if (tid < 18) part[(size_t)blockIdx.x * 18 + tid] = loc[tid];
}

// Single block: reduce edge partials (ER_BLOCKS x 18) + cs partials (PB x 16),
// compute the 3 scalar losses.
__global__ __launch_bounds__(256) void finalize(const float* __restrict__ epart,
                                                const float* __restrict__ cs_part,
                                                int pool_blocks,
                                                float* __restrict__ out,
                                                int N, int s_elems) {
  __shared__ float red[18];
  __shared__ float csl[256];
  __shared__ float cs[16];
  int tid = threadIdx.x;
  if (tid < 18) {
    float a = 0.f;
    for (int b = 0; b < ER_BLOCKS; ++b) a += epart[(size_t)b * 18 + tid];
    red[tid] = a;
  }
  {  // cs: col = tid&15, slice = tid>>4 (16 slices over pool_blocks)
    int k = tid & 15, sl = tid >> 4;
    float a = 0.f;
    for (int b = sl; b < pool_blocks; b += 16) a += cs_part[(size_t)b * 16 + k];
    csl[tid] = a;
  }
  __syncthreads();
  if (tid < 16) {
    float a = 0.f;
#pragma unroll
    for (int sl = 0; sl < 16; ++sl) a += csl[sl * 16 + tid];
    cs[tid] = a;
  }
  __syncthreads();
  if (tid == 0) {
    float tr = red[0], m2 = red[1];  // m2 = 2m = sum(ew)
    float ca2 = 0.f, cs2 = 0.f;
    for (int k = 0; k < 16; ++k) {
      ca2 += red[2 + k] * red[2 + k];
      cs2 += cs[k] * cs[k];
    }
    float sp = -(tr - ca2 / m2) / m2;
    float cl = sqrtf(cs2) / (float)N * 4.0f - 1.0f;  // sqrt(K)=4
    out[s_elems + 0] = 100.f * (sp + cl);
    out[s_elems + 1] = 100.f * sp;
    out[s_elems + 2] = 100.f * cl;
  }
}

extern "C" void kernel_launch(void* const* d_in, const int* in_sizes, int n_in,
                              void* d_out, int out_size, void* d_ws, size_t ws_size,
                              hipStream_t stream) {
  const float* x  = (const float*)d_in[0];
  const int*   ei = (const int*)d_in[1];   // int32 or int64 (device-detected)
  const float* ew = (const float*)d_in[2];
  const float* W1 = (const float*)d_in[3];
  const float* b1 = (const float*)d_in[4];
  const float* W2 = (const float*)d_in[5];
  const float* b2 = (const float*)d_in[6];
  const float* Wp = (const float*)d_in[7];
  const float* bp = (const float*)d_in[8];
  float* out = (float*)d_out;

  const int IN_C = 128, HID = 256;
  const int N = in_sizes[0] / IN_C;   // 10000
  const int E = in_sizes[2];          // 160000
  const int pool_blocks = (N + 15) / 16;

  // workspace carve (aligned 256B). deg|cnt|cur FIRST and adjacent so one
  // zero_init kernel covers all three (incl. 256B pads).
  char* p = (char*)d_ws;
  auto alloc = [&](size_t b) { char* r = p; p += (b + 255) & ~(size_t)255; return r; };
  float* deg     = (float*)alloc((size_t)N * 4);
  int*   cnt     = (int*)alloc((size_t)N * 4);
  int*   cur     = (int*)alloc((size_t)N * 4);
  char*  zero_end = p;
  float* ht      = (float*)alloc((size_t)N * HID * 4);
  float* h       = (float*)alloc((size_t)N * HID * 4);
  float* dis     = (float*)alloc((size_t)N * 4);
  int*   rowptr  = (int*)alloc((size_t)(N + 1) * 4);
  int*   col     = (int*)alloc((size_t)E * 4);
  float* coef    = (float*)alloc((size_t)E * 4);
  float* epart   = (float*)alloc((size_t)ER_BLOCKS * 18 * 4);
  float* cs_part = (float*)alloc((size_t)pool_blocks * 16 * 4);
  if ((size_t)(p - (char*)d_ws) > ws_size) return;  // fail loudly via poison

  int zn4 = (int)((zero_end - (char*)deg) >> 4);  // int4 count (256B-padded)
  zero_init<<<(zn4 + 255) / 256, 256, 0, stream>>>((int4*)deg, zn4);

  int eb = (E + 255) / 256;
  edge_count<<<eb, 256, 0, stream>>>(ei, ew, cnt, deg, E);
  scan_kernel<<<1, 1024, 0, stream>>>(cnt, rowptr, deg, dis, N);
  scatter_edges<<<eb, 256, 0, stream>>>(ei, ew, rowptr, cur, dis, col, coef, E);

  dim3 gg((N + 63) / 64, HID / 64);
  gemm_f32<<<gg, 256, 0, stream>>>(x, W1, ht, N, IN_C, HID);
  aggregate<<<N, 256, 0, stream>>>(ht, rowptr, col, coef, dis, b1, h, N);
  gemm_f32<<<gg, 256, 0, stream>>>(h, W2, ht, N, HID, HID);
  aggregate<<<N, 256, 0, stream>>>(ht, rowptr, col, coef, dis, b2, h, N);

  pool_kernel<<<pool_blocks, 256, 0, stream>>>(h, Wp, bp, out, cs_part, N);
  edge_reduce<<<ER_BLOCKS, 256, 0, stream>>>(ei, ew, out, epart, E);
  finalize<<<1, 256, 0, stream>>>(epart, cs_part, pool_blocks, out, N, N * 16);
}

// Round 5
// 166.829 us; speedup vs baseline: 4.2844x; 1.2313x over previous
//
#include <hip/hip_runtime.h>
#include <math.h>

// ---------------------------------------------------------------------------
// DMoN pooling, edge-list formulation (dense adj never materialized).
//   0. zero_init: deg/cnt/cur
//   1. CSR-by-dst build (count / scan / scatter-with-inline-rsqrt)
//   2. layer 1: ax = aggregate(x)  [GCN linearity: agg before GEMM, 128ch]
//               h  = relu(ax@W1 + b1)   (bias+relu fused in GEMM epilogue)
//   3. layer 2: ah = aggregate(h) ; h2 = relu(ah@W2 + b2)
//   4. s = softmax(h2@Wp + bp) -> d_out ; per-block cluster-size partials
//   5. per-edge reduction -> per-block partials (NO global atomics)
//   6. finalize: reduce partials, emit 3 scalars
// ---------------------------------------------------------------------------

#define ER_BLOCKS 128  // edge_reduce grid; partials buffer sized to match

// edge_index declared int64 in the reference, but JAX without x64 keeps int32.
// Detect on device: int64 little-endian small ids => odd 32-bit words are 0.
__device__ __forceinline__ bool ei_is_i64(const int* __restrict__ ei) {
  return ((ei[1] | ei[3] | ei[5] | ei[7]) == 0);
}
__device__ __forceinline__ int ld_idx(const int* __restrict__ ei, int pos, bool i64) {
  return i64 ? ei[2 * pos] : ei[pos];
}

__global__ __launch_bounds__(256) void zero_init(int4* __restrict__ p, int n4) {
  int i = blockIdx.x * 256 + threadIdx.x;
  if (i < n4) p[i] = make_int4(0, 0, 0, 0);
}

__global__ __launch_bounds__(256) void edge_count(const int* __restrict__ ei,
                                                  const float* __restrict__ ew,
                                                  int* __restrict__ cnt,
                                                  float* __restrict__ deg, int E) {
  int e = blockIdx.x * 256 + threadIdx.x;
  if (e >= E) return;
  bool i64 = ei_is_i64(ei);
  int d = ld_idx(ei, E + e, i64);
  atomicAdd(&cnt[d], 1);
  atomicAdd(&deg[d], ew[e]);
}

// Single block: chunked scan of cnt -> rowptr.
__global__ __launch_bounds__(1024) void scan_kernel(const int* __restrict__ cnt,
                                                    int* __restrict__ rowptr, int n) {
  __shared__ int sums[1024];
  int tid = threadIdx.x;
  int CH = (n + 1023) >> 10;
  int beg = tid * CH, end = min(beg + CH, n);
  int s = 0;
  for (int i = beg; i < end; ++i) s += cnt[i];
  sums[tid] = s;
  __syncthreads();
  for (int off = 1; off < 1024; off <<= 1) {
    int v = (tid >= off) ? sums[tid - off] : 0;
    __syncthreads();
    sums[tid] += v;
    __syncthreads();
  }
  int run = (tid == 0) ? 0 : sums[tid - 1];
  for (int i = beg; i < end; ++i) { rowptr[i] = run; run += cnt[i]; }
  if (tid == 1023) rowptr[n] = run;
}

__global__ __launch_bounds__(256) void scatter_edges(const int* __restrict__ ei,
                                                     const float* __restrict__ ew,
                                                     const int* __restrict__ rowptr,
                                                     int* __restrict__ cur,
                                                     const float* __restrict__ deg,
                                                     int* __restrict__ col,
                                                     float* __restrict__ coef, int E) {
  int e = blockIdx.x * 256 + threadIdx.x;
  if (e >= E) return;
  bool i64 = ei_is_i64(ei);
  int s = ld_idx(ei, e, i64);
  int d = ld_idx(ei, E + e, i64);
  int p = rowptr[d] + atomicAdd(&cur[d], 1);
  col[p] = s;
  float ds = 1.0f / sqrtf(deg[s] + 1.0f);   // +1 = self-loop weight
  float dd = 1.0f / sqrtf(deg[d] + 1.0f);
  coef[p] = ds * ew[e] * dd;
}

// Normalized aggregation WITHOUT transform (runs before the GEMM):
//   out[i] = (1/(deg_i+1)) * src[i] + sum_p coef[p] * src[col[p]]
// thread = (slot, quad): NS independent edge streams, float4 gather loads.
template <int CH>
__global__ __launch_bounds__(256) void aggregate_pre(const float* __restrict__ src,
                                                     const int* __restrict__ rowptr,
                                                     const int* __restrict__ col,
                                                     const float* __restrict__ coef,
                                                     const float* __restrict__ deg,
                                                     float* __restrict__ out, int N) {
  constexpr int Q = CH / 4;    // float4 lanes per row (32 or 64)
  constexpr int NS = 256 / Q;  // concurrent edge slots (8 or 4)
  int i = blockIdx.x;
  int t = threadIdx.x;
  int q = t % Q, slot = t / Q;
  int e0 = rowptr[i], e1 = rowptr[i + 1];
  float4 acc = make_float4(0.f, 0.f, 0.f, 0.f);
  for (int p = e0 + slot; p < e1; p += NS) {
    int c = col[p];
    float w = coef[p];
    float4 v = *reinterpret_cast<const float4*>(&src[(size_t)c * CH + q * 4]);
    acc.x += w * v.x; acc.y += w * v.y; acc.z += w * v.z; acc.w += w * v.w;
  }
  __shared__ float4 red[256];
  red[t] = acc;
  __syncthreads();
  if (slot == 0) {
#pragma unroll
    for (int s2 = 1; s2 < NS; ++s2) {
      float4 o = red[s2 * Q + q];
      acc.x += o.x; acc.y += o.y; acc.z += o.z; acc.w += o.w;
    }
    float w0 = 1.0f / (deg[i] + 1.0f);  // dis_i^2, self-loop term
    float4 xv = *reinterpret_cast<const float4*>(&src[(size_t)i * CH + q * 4]);
    acc.x += w0 * xv.x; acc.y += w0 * xv.y; acc.z += w0 * xv.z; acc.w += w0 * xv.w;
    *reinterpret_cast<float4*>(&out[(size_t)i * CH + q * 4]) = acc;
  }
}

// C[M,N] = act(A[M,K] @ B[K,N] + bias); 64x64 tile, 256 threads, 4x4 microtile.
// A-tile stored TRANSPOSED in LDS so the a-fragment is one ds_read_b128.
__global__ __launch_bounds__(256) void gemm_bias_act(const float* __restrict__ A,
                                                     const float* __restrict__ B,
                                                     const float* __restrict__ bias,
                                                     float* __restrict__ C,
                                                     int M, int K, int N, int relu) {
  __shared__ float As[32][68];  // [k][m], +4 pad
  __shared__ float Bs[32][64];  // [k][n]
  int tid = threadIdx.x;
  int tx = tid & 15, ty = tid >> 4;
  int row0 = blockIdx.x * 64, col0 = blockIdx.y * 64;
  float acc[4][4] = {};
  for (int k0 = 0; k0 < K; k0 += 32) {
#pragma unroll
    for (int r = 0; r < 2; ++r) {
      int lin = (tid + r * 256) * 4;  // 0..2047
      int ar = lin >> 5, ak = lin & 31;
      float4 av = make_float4(0.f, 0.f, 0.f, 0.f);
      int grow = row0 + ar;
      if (grow < M) av = *reinterpret_cast<const float4*>(&A[(size_t)grow * K + k0 + ak]);
      As[ak + 0][ar] = av.x; As[ak + 1][ar] = av.y;
      As[ak + 2][ar] = av.z; As[ak + 3][ar] = av.w;
      int bk = lin >> 6, bn = lin & 63;
      float4 bv = *reinterpret_cast<const float4*>(&B[(size_t)(k0 + bk) * N + col0 + bn]);
      *reinterpret_cast<float4*>(&Bs[bk][bn]) = bv;
    }
    __syncthreads();
#pragma unroll
    for (int k = 0; k < 32; ++k) {
      float4 av = *reinterpret_cast<const float4*>(&As[k][ty * 4]);
      float4 bv = *reinterpret_cast<const float4*>(&Bs[k][tx * 4]);
      float a[4] = {av.x, av.y, av.z, av.w};
      float b[4] = {bv.x, bv.y, bv.z, bv.w};
#pragma unroll
      for (int i = 0; i < 4; ++i)
#pragma unroll
        for (int j = 0; j < 4; ++j) acc[i][j] += a[i] * b[j];
    }
    __syncthreads();
  }
  float4 bb = *reinterpret_cast<const float4*>(&bias[col0 + tx * 4]);
  float bias4[4] = {bb.x, bb.y, bb.z, bb.w};
#pragma unroll
  for (int i = 0; i < 4; ++i) {
    int gr = row0 + ty * 4 + i;
    if (gr < M) {
      float o[4];
#pragma unroll
      for (int j = 0; j < 4; ++j) {
        float v = acc[i][j] + bias4[j];
        o[j] = relu ? fmaxf(v, 0.0f) : v;
      }
      *reinterpret_cast<float4*>(&C[(size_t)gr * N + col0 + tx * 4]) =
          make_float4(o[0], o[1], o[2], o[3]);
    }
  }
}

// Pooling: lane = (group g, cluster k); wave handles 4 nodes. Softmax over 16
// via intra-group shuffles; writes s coalesced; per-block cluster-size
// partials to a PRIVATE workspace slot (no global atomics).
__global__ __launch_bounds__(256) void pool_kernel(const float* __restrict__ h,
                                                   const float* __restrict__ Wp,
                                                   const float* __restrict__ bp,
                                                   float* __restrict__ s_out,
                                                   float* __restrict__ cs_part, int N) {
  __shared__ float Wps[256 * 16];  // natural [c][k] layout: conflict-free reads
  __shared__ float cs_loc[16];
  int tid = threadIdx.x;
  for (int idx = tid; idx < 4096; idx += 256) Wps[idx] = Wp[idx];
  if (tid < 16) cs_loc[tid] = 0.f;
  __syncthreads();
  int lane = tid & 63;
  int wave = tid >> 6;
  int k = lane & 15, g = lane >> 4;
  int node = blockIdx.x * 16 + wave * 4 + g;
  float acc = 0.f;
  if (node < N) {
    const float4* hrow = reinterpret_cast<const float4*>(h + (size_t)node * 256);
#pragma unroll 8
    for (int c4 = 0; c4 < 64; ++c4) {
      float4 hv = hrow[c4];
      int cb = c4 * 4;
      acc += hv.x * Wps[(cb + 0) * 16 + k];
      acc += hv.y * Wps[(cb + 1) * 16 + k];
      acc += hv.z * Wps[(cb + 2) * 16 + k];
      acc += hv.w * Wps[(cb + 3) * 16 + k];
    }
    acc += bp[k];
  }
  float mx = acc;
#pragma unroll
  for (int off = 1; off < 16; off <<= 1) mx = fmaxf(mx, __shfl_xor(mx, off));
  float ex = (node < N) ? expf(acc - mx) : 0.f;
  float sm = ex;
#pragma unroll
  for (int off = 1; off < 16; off <<= 1) sm += __shfl_xor(sm, off);
  float sval = (node < N) ? ex / sm : 0.f;
  if (node < N) s_out[(size_t)node * 16 + k] = sval;
  float v = sval;
  v += __shfl_xor(v, 16);
  v += __shfl_xor(v, 32);
  if (lane < 16) atomicAdd(&cs_loc[lane], v);  // LDS atomic: cheap
  __syncthreads();
  if (tid < 16) cs_part[(size_t)blockIdx.x * 16 + tid] = cs_loc[tid];
}

// Per-edge: dot += w*dot(s_src,s_dst); ca[k] += w*s_src[k]; sumw += w.
// Grid-stride over ER_BLOCKS blocks; per-block partials (no global atomics).
__global__ __launch_bounds__(256) void edge_reduce(const int* __restrict__ ei,
                                                   const float* __restrict__ ew,
                                                   const float* __restrict__ s,
                                                   float* __restrict__ part, int E) {
  __shared__ float loc[18];
  int tid = threadIdx.x;
  if (tid < 18) loc[tid] = 0.f;
  __syncthreads();
  bool i64 = ei_is_i64(ei);
  float dot = 0.f, w = 0.f;
  float ca[16];
#pragma unroll
  for (int k = 0; k < 16; ++k) ca[k] = 0.f;
  for (int e = blockIdx.x * 256 + tid; e < E; e += gridDim.x * 256) {
    int a = ld_idx(ei, e, i64);
    int b = ld_idx(ei, E + e, i64);
    float we = ew[e];
    const float4* sa = reinterpret_cast<const float4*>(s + (size_t)a * 16);
    const float4* sb = reinterpret_cast<const float4*>(s + (size_t)b * 16);
    float d = 0.f;
#pragma unroll
    for (int q = 0; q < 4; ++q) {
      float4 av = sa[q], bv = sb[q];
      d += av.x * bv.x + av.y * bv.y + av.z * bv.z + av.w * bv.w;
      ca[q * 4 + 0] += we * av.x; ca[q * 4 + 1] += we * av.y;
      ca[q * 4 + 2] += we * av.z; ca[q * 4 + 3] += we * av.w;
    }
    dot += we * d;
    w += we;
  }
#pragma unroll
  for (int off = 32; off; off >>= 1) {
    dot += __shfl_xor(dot, off);
    w += __shfl_xor(w, off);
#pragma unroll
    for (int k = 0; k < 16; ++k) ca[k] += __shfl_xor(ca[k], off);
  }
  if ((tid & 63) == 0) {  // lane 0 of each wave: LDS atomics (4 waves x 18)
    atomicAdd(&loc[0], dot);
    atomicAdd(&loc[1], w);
#pragma unroll
    for (int k = 0; k < 16; ++k) atomicAdd(&loc[2 + k], ca[k]);
  }
  __syncthreads();
  if (tid < 18) part[(size_t)blockIdx.x * 18 + tid] = loc[tid];
}

// Single block: reduce edge partials (ER_BLOCKS x 18) + cs partials (PB x 16),
// compute the 3 scalar losses.
__global__ __launch_bounds__(256) void finalize(const float* __restrict__ epart,
                                                const float* __restrict__ cs_part,
                                                int pool_blocks,
                                                float* __restrict__ out,
                                                int N, int s_elems) {
  __shared__ float red[18];
  __shared__ float csl[256];
  __shared__ float cs[16];
  int tid = threadIdx.x;
  if (tid < 18) {
    float a = 0.f;
    for (int b = 0; b < ER_BLOCKS; ++b) a += epart[(size_t)b * 18 + tid];
    red[tid] = a;
  }
  {  // cs: col = tid&15, slice = tid>>4 (16 slices over pool_blocks)
    int k = tid & 15, sl = tid >> 4;
    float a = 0.f;
    for (int b = sl; b < pool_blocks; b += 16) a += cs_part[(size_t)b * 16 + k];
    csl[tid] = a;
  }
  __syncthreads();
  if (tid < 16) {
    float a = 0.f;
#pragma unroll
    for (int sl = 0; sl < 16; ++sl) a += csl[sl * 16 + tid];
    cs[tid] = a;
  }
  __syncthreads();
  if (tid == 0) {
    float tr = red[0], m2 = red[1];  // m2 = 2m = sum(ew)
    float ca2 = 0.f, cs2 = 0.f;
    for (int k = 0; k < 16; ++k) {
      ca2 += red[2 + k] * red[2 + k];
      cs2 += cs[k] * cs[k];
    }
    float sp = -(tr - ca2 / m2) / m2;
    float cl = sqrtf(cs2) / (float)N * 4.0f - 1.0f;  // sqrt(K)=4
    out[s_elems + 0] = 100.f * (sp + cl);
    out[s_elems + 1] = 100.f * sp;
    out[s_elems + 2] = 100.f * cl;
  }
}

extern "C" void kernel_launch(void* const* d_in, const int* in_sizes, int n_in,
                              void* d_out, int out_size, void* d_ws, size_t ws_size,
                              hipStream_t stream) {
  const float* x  = (const float*)d_in[0];
  const int*   ei = (const int*)d_in[1];   // int32 or int64 (device-detected)
  const float* ew = (const float*)d_in[2];
  const float* W1 = (const float*)d_in[3];
  const float* b1 = (const float*)d_in[4];
  const float* W2 = (const float*)d_in[5];
  const float* b2 = (const float*)d_in[6];
  const float* Wp = (const float*)d_in[7];
  const float* bp = (const float*)d_in[8];
  float* out = (float*)d_out;

  const int IN_C = 128, HID = 256;
  const int N = in_sizes[0] / IN_C;   // 10000
  const int E = in_sizes[2];          // 160000
  const int pool_blocks = (N + 15) / 16;

  // workspace carve (aligned 256B). deg|cnt|cur FIRST and adjacent so one
  // zero_init kernel covers all three (incl. 256B pads).
  char* p = (char*)d_ws;
  auto alloc = [&](size_t b) { char* r = p; p += (b + 255) & ~(size_t)255; return r; };
  float* deg     = (float*)alloc((size_t)N * 4);
  int*   cnt     = (int*)alloc((size_t)N * 4);
  int*   cur     = (int*)alloc((size_t)N * 4);
  char*  zero_end = p;
  float* ax      = (float*)alloc((size_t)N * IN_C * 4);  // aggregated x
  float* h       = (float*)alloc((size_t)N * HID * 4);   // layer outputs
  float* ah      = (float*)alloc((size_t)N * HID * 4);   // aggregated h / h2
  float* h2      = (float*)alloc((size_t)N * HID * 4);
  int*   rowptr  = (int*)alloc((size_t)(N + 1) * 4);
  int*   col     = (int*)alloc((size_t)E * 4);
  float* coef    = (float*)alloc((size_t)E * 4);
  float* epart   = (float*)alloc((size_t)ER_BLOCKS * 18 * 4);
  float* cs_part = (float*)alloc((size_t)pool_blocks * 16 * 4);
  if ((size_t)(p - (char*)d_ws) > ws_size) return;  // fail loudly via poison

  int zn4 = (int)((zero_end - (char*)deg) >> 4);  // int4 count (256B-padded)
  zero_init<<<(zn4 + 255) / 256, 256, 0, stream>>>((int4*)deg, zn4);

  int eb = (E + 255) / 256;
  edge_count<<<eb, 256, 0, stream>>>(ei, ew, cnt, deg, E);
  scan_kernel<<<1, 1024, 0, stream>>>(cnt, rowptr, N);
  scatter_edges<<<eb, 256, 0, stream>>>(ei, ew, rowptr, cur, deg, col, coef, E);

  // layer 1: aggregate(x) then transform
  aggregate_pre<128><<<N, 256, 0, stream>>>(x, rowptr, col, coef, deg, ax, N);
  dim3 gg((N + 63) / 64, HID / 64);
  gemm_bias_act<<<gg, 256, 0, stream>>>(ax, W1, b1, h, N, IN_C, HID, 1);
  // layer 2
  aggregate_pre<256><<<N, 256, 0, stream>>>(h, rowptr, col, coef, deg, ah, N);
  gemm_bias_act<<<gg, 256, 0, stream>>>(ah, W2, b2, h2, N, HID, HID, 1);

  pool_kernel<<<pool_blocks, 256, 0, stream>>>(h2, Wp, bp, out, cs_part, N);
  edge_reduce<<<ER_BLOCKS, 256, 0, stream>>>(ei, ew, out, epart, E);
  finalize<<<1, 256, 0, stream>>>(epart, cs_part, pool_blocks, out, N, N * 16);
}

// Round 6
// 153.746 us; speedup vs baseline: 4.6490x; 1.0851x over previous
//
#include <hip/hip_runtime.h>
#include <math.h>

// ---------------------------------------------------------------------------
// DMoN pooling, edge-list formulation (dense adj never materialized).
//   0. zero_init (deg/cnt/cur) ; conv_weights: W1,W2 -> transposed bf16 hi/lo
//   1. CSR-by-dst build (count / scan / scatter-with-inline-rsqrt)
//   2. layer 1: (axhi,axlo) = split_bf16(aggregate(x))   [agg before GEMM]
//               h  = relu(ax@W1 + b1)    via 3-term bf16 MFMA GEMM
//   3. layer 2: (ahhi,ahlo) = split_bf16(aggregate(h)) ; h2 = relu(ah@W2+b2)
//   4. s = softmax(h2@Wp + bp) -> d_out ; per-block cluster-size partials
//   5. per-edge reduction -> per-block partials (NO global atomics)
//   6. finalize: reduce partials, emit 3 scalars
// ---------------------------------------------------------------------------

#define ER_BLOCKS 128

typedef unsigned short u16;
typedef __attribute__((ext_vector_type(8))) short short8v;
typedef __attribute__((ext_vector_type(4))) float float4v;
typedef __attribute__((ext_vector_type(4))) unsigned short ushort4v;

// fp32 -> bf16 round-to-nearest-even (bit trick; inputs finite)
__device__ __forceinline__ u16 f2bf_rne(float x) {
  unsigned u = __float_as_uint(x);
  u = (u + 0x7fffu + ((u >> 16) & 1u)) >> 16;
  return (u16)u;
}
__device__ __forceinline__ float bf2f(u16 h) {
  return __uint_as_float(((unsigned)h) << 16);
}

// edge_index declared int64 in the reference, but JAX without x64 keeps int32.
__device__ __forceinline__ bool ei_is_i64(const int* __restrict__ ei) {
  return ((ei[1] | ei[3] | ei[5] | ei[7]) == 0);
}
__device__ __forceinline__ int ld_idx(const int* __restrict__ ei, int pos, bool i64) {
  return i64 ? ei[2 * pos] : ei[pos];
}

__global__ __launch_bounds__(256) void zero_init(int4* __restrict__ p, int n4) {
  int i = blockIdx.x * 256 + threadIdx.x;
  if (i < n4) p[i] = make_int4(0, 0, 0, 0);
}

// W1[128][256], W2[256][256] fp32 -> transposed [n][k] bf16 hi/lo.
__global__ __launch_bounds__(256) void conv_weights(const float* __restrict__ W1,
                                                    const float* __restrict__ W2,
                                                    u16* __restrict__ w1hi, u16* __restrict__ w1lo,
                                                    u16* __restrict__ w2hi, u16* __restrict__ w2lo) {
  const int T1 = 256 * 128;  // W1t elems
  const int T2 = 256 * 256;
  int t = blockIdx.x * 256 + threadIdx.x;
  if (t < T1) {
    int n = t >> 7, k = t & 127;
    float x = W1[k * 256 + n];
    u16 h = f2bf_rne(x);
    w1hi[t] = h;
    w1lo[t] = f2bf_rne(x - bf2f(h));
  } else if (t < T1 + T2) {
    int t2 = t - T1;
    int n = t2 >> 8, k = t2 & 255;
    float x = W2[k * 256 + n];
    u16 h = f2bf_rne(x);
    w2hi[t2] = h;
    w2lo[t2] = f2bf_rne(x - bf2f(h));
  }
}

__global__ __launch_bounds__(256) void edge_count(const int* __restrict__ ei,
                                                  const float* __restrict__ ew,
                                                  int* __restrict__ cnt,
                                                  float* __restrict__ deg, int E) {
  int e = blockIdx.x * 256 + threadIdx.x;
  if (e >= E) return;
  bool i64 = ei_is_i64(ei);
  int d = ld_idx(ei, E + e, i64);
  atomicAdd(&cnt[d], 1);
  atomicAdd(&deg[d], ew[e]);
}

__global__ __launch_bounds__(1024) void scan_kernel(const int* __restrict__ cnt,
                                                    int* __restrict__ rowptr, int n) {
  __shared__ int sums[1024];
  int tid = threadIdx.x;
  int CH = (n + 1023) >> 10;
  int beg = tid * CH, end = min(beg + CH, n);
  int s = 0;
  for (int i = beg; i < end; ++i) s += cnt[i];
  sums[tid] = s;
  __syncthreads();
  for (int off = 1; off < 1024; off <<= 1) {
    int v = (tid >= off) ? sums[tid - off] : 0;
    __syncthreads();
    sums[tid] += v;
    __syncthreads();
  }
  int run = (tid == 0) ? 0 : sums[tid - 1];
  for (int i = beg; i < end; ++i) { rowptr[i] = run; run += cnt[i]; }
  if (tid == 1023) rowptr[n] = run;
}

__global__ __launch_bounds__(256) void scatter_edges(const int* __restrict__ ei,
                                                     const float* __restrict__ ew,
                                                     const int* __restrict__ rowptr,
                                                     int* __restrict__ cur,
                                                     const float* __restrict__ deg,
                                                     int* __restrict__ col,
                                                     float* __restrict__ coef, int E) {
  int e = blockIdx.x * 256 + threadIdx.x;
  if (e >= E) return;
  bool i64 = ei_is_i64(ei);
  int s = ld_idx(ei, e, i64);
  int d = ld_idx(ei, E + e, i64);
  int p = rowptr[d] + atomicAdd(&cur[d], 1);
  col[p] = s;
  float ds = 1.0f / sqrtf(deg[s] + 1.0f);
  float dd = 1.0f / sqrtf(deg[d] + 1.0f);
  coef[p] = ds * ew[e] * dd;
}

// Normalized aggregation (pre-GEMM); epilogue splits result to bf16 hi/lo.
template <int CH>
__global__ __launch_bounds__(256) void aggregate_pre(const float* __restrict__ src,
                                                     const int* __restrict__ rowptr,
                                                     const int* __restrict__ col,
                                                     const float* __restrict__ coef,
                                                     const float* __restrict__ deg,
                                                     u16* __restrict__ ohi,
                                                     u16* __restrict__ olo, int N) {
  constexpr int Q = CH / 4;
  constexpr int NS = 256 / Q;
  int i = blockIdx.x;
  int t = threadIdx.x;
  int q = t % Q, slot = t / Q;
  int e0 = rowptr[i], e1 = rowptr[i + 1];
  float4 acc = make_float4(0.f, 0.f, 0.f, 0.f);
  for (int p = e0 + slot; p < e1; p += NS) {
    int c = col[p];
    float w = coef[p];
    float4 v = *reinterpret_cast<const float4*>(&src[(size_t)c * CH + q * 4]);
    acc.x += w * v.x; acc.y += w * v.y; acc.z += w * v.z; acc.w += w * v.w;
  }
  __shared__ float4 red[256];
  red[t] = acc;
  __syncthreads();
  if (slot == 0) {
#pragma unroll
    for (int s2 = 1; s2 < NS; ++s2) {
      float4 o = red[s2 * Q + q];
      acc.x += o.x; acc.y += o.y; acc.z += o.z; acc.w += o.w;
    }
    float w0 = 1.0f / (deg[i] + 1.0f);
    float4 xv = *reinterpret_cast<const float4*>(&src[(size_t)i * CH + q * 4]);
    acc.x += w0 * xv.x; acc.y += w0 * xv.y; acc.z += w0 * xv.z; acc.w += w0 * xv.w;
    float a[4] = {acc.x, acc.y, acc.z, acc.w};
    ushort4v hv, lv;
#pragma unroll
    for (int j = 0; j < 4; ++j) {
      u16 h = f2bf_rne(a[j]);
      hv[j] = h;
      lv[j] = f2bf_rne(a[j] - bf2f(h));
    }
    *reinterpret_cast<ushort4v*>(&ohi[(size_t)i * CH + q * 4]) = hv;
    *reinterpret_cast<ushort4v*>(&olo[(size_t)i * CH + q * 4]) = lv;
  }
}

// C[M,256] = relu(A@B + bias) via bf16 MFMA, A = Ahi+Alo, B = Bhi+Blo (3 terms).
// A: [M][K] bf16 hi/lo row-major. Wt: [256][K] bf16 hi/lo (B transposed).
// 64x64 tile, 4 waves (2x2), wave = 32x32 = 2x2 mfma_16x16x32 fragments.
__global__ __launch_bounds__(256) void gemm_mfma(const u16* __restrict__ Ahi,
                                                 const u16* __restrict__ Alo,
                                                 const u16* __restrict__ Wthi,
                                                 const u16* __restrict__ Wtlo,
                                                 const float* __restrict__ bias,
                                                 float* __restrict__ C,
                                                 int M, int K) {
  __shared__ u16 As_hi[64][40], As_lo[64][40];  // [m][k], pad 32->40 (2-way banks)
  __shared__ u16 Bs_hi[64][40], Bs_lo[64][40];  // [n][k]
  int tid = threadIdx.x;
  int w = tid >> 6, l = tid & 63;
  int wm = w >> 1, wn = w & 1;
  int row0 = blockIdx.x * 64, col0 = blockIdx.y * 64;
  int srow = tid >> 2, sc = (tid & 3) * 8;  // staging: 64 rows x 4 chunks of 8
  int fr = l & 15, kg = (l >> 4) * 8;       // fragment row / k-group

  float4v acc[2][2];
#pragma unroll
  for (int i = 0; i < 2; ++i)
#pragma unroll
    for (int j = 0; j < 2; ++j) acc[i][j] = (float4v){0.f, 0.f, 0.f, 0.f};

  for (int k0 = 0; k0 < K; k0 += 32) {
    {  // stage A hi/lo (M-guarded) and B hi/lo
      int gr = row0 + srow;
      uint4 zero = make_uint4(0, 0, 0, 0);
      uint4 vh = zero, vl = zero;
      if (gr < M) {
        vh = *reinterpret_cast<const uint4*>(&Ahi[(size_t)gr * K + k0 + sc]);
        vl = *reinterpret_cast<const uint4*>(&Alo[(size_t)gr * K + k0 + sc]);
      }
      *reinterpret_cast<uint4*>(&As_hi[srow][sc]) = vh;
      *reinterpret_cast<uint4*>(&As_lo[srow][sc]) = vl;
      int bn = col0 + srow;
      uint4 bh = *reinterpret_cast<const uint4*>(&Wthi[(size_t)bn * K + k0 + sc]);
      uint4 bl = *reinterpret_cast<const uint4*>(&Wtlo[(size_t)bn * K + k0 + sc]);
      *reinterpret_cast<uint4*>(&Bs_hi[srow][sc]) = bh;
      *reinterpret_cast<uint4*>(&Bs_lo[srow][sc]) = bl;
    }
    __syncthreads();
    short8v ah[2], al[2], bh[2], bl[2];
#pragma unroll
    for (int i = 0; i < 2; ++i) {
      int r = wm * 32 + i * 16 + fr;
      ah[i] = *reinterpret_cast<const short8v*>(&As_hi[r][kg]);
      al[i] = *reinterpret_cast<const short8v*>(&As_lo[r][kg]);
    }
#pragma unroll
    for (int j = 0; j < 2; ++j) {
      int n = wn * 32 + j * 16 + fr;
      bh[j] = *reinterpret_cast<const short8v*>(&Bs_hi[n][kg]);
      bl[j] = *reinterpret_cast<const short8v*>(&Bs_lo[n][kg]);
    }
#pragma unroll
    for (int i = 0; i < 2; ++i)
#pragma unroll
      for (int j = 0; j < 2; ++j) {
        acc[i][j] = __builtin_amdgcn_mfma_f32_16x16x32_bf16(ah[i], bh[j], acc[i][j], 0, 0, 0);
        acc[i][j] = __builtin_amdgcn_mfma_f32_16x16x32_bf16(al[i], bh[j], acc[i][j], 0, 0, 0);
        acc[i][j] = __builtin_amdgcn_mfma_f32_16x16x32_bf16(ah[i], bl[j], acc[i][j], 0, 0, 0);
      }
    __syncthreads();
  }
  // epilogue: C/D layout col = lane&15, row = (lane>>4)*4 + reg
#pragma unroll
  for (int j = 0; j < 2; ++j) {
    int gc = col0 + wn * 32 + j * 16 + fr;
    float bj = bias[gc];
#pragma unroll
    for (int i = 0; i < 2; ++i) {
#pragma unroll
      for (int r = 0; r < 4; ++r) {
        int gr = row0 + wm * 32 + i * 16 + (l >> 4) * 4 + r;
        if (gr < M) {
          float v = acc[i][j][r] + bj;
          C[(size_t)gr * 256 + gc] = fmaxf(v, 0.0f);
        }
      }
    }
  }
}

// Pooling + softmax + per-block cluster-size partials.
__global__ __launch_bounds__(256) void pool_kernel(const float* __restrict__ h,
                                                   const float* __restrict__ Wp,
                                                   const float* __restrict__ bp,
                                                   float* __restrict__ s_out,
                                                   float* __restrict__ cs_part, int N) {
  __shared__ float Wps[256 * 16];
  __shared__ float cs_loc[16];
  int tid = threadIdx.x;
  for (int idx = tid; idx < 4096; idx += 256) Wps[idx] = Wp[idx];
  if (tid < 16) cs_loc[tid] = 0.f;
  __syncthreads();
  int lane = tid & 63;
  int wave = tid >> 6;
  int k = lane & 15, g = lane >> 4;
  int node = blockIdx.x * 16 + wave * 4 + g;
  float acc = 0.f;
  if (node < N) {
    const float4* hrow = reinterpret_cast<const float4*>(h + (size_t)node * 256);
#pragma unroll 8
    for (int c4 = 0; c4 < 64; ++c4) {
      float4 hv = hrow[c4];
      int cb = c4 * 4;
      acc += hv.x * Wps[(cb + 0) * 16 + k];
      acc += hv.y * Wps[(cb + 1) * 16 + k];
      acc += hv.z * Wps[(cb + 2) * 16 + k];
      acc += hv.w * Wps[(cb + 3) * 16 + k];
    }
    acc += bp[k];
  }
  float mx = acc;
#pragma unroll
  for (int off = 1; off < 16; off <<= 1) mx = fmaxf(mx, __shfl_xor(mx, off));
  float ex = (node < N) ? expf(acc - mx) : 0.f;
  float sm = ex;
#pragma unroll
  for (int off = 1; off < 16; off <<= 1) sm += __shfl_xor(sm, off);
  float sval = (node < N) ? ex / sm : 0.f;
  if (node < N) s_out[(size_t)node * 16 + k] = sval;
  float v = sval;
  v += __shfl_xor(v, 16);
  v += __shfl_xor(v, 32);
  if (lane < 16) atomicAdd(&cs_loc[lane], v);
  __syncthreads();
  if (tid < 16) cs_part[(size_t)blockIdx.x * 16 + tid] = cs_loc[tid];
}

// Per-edge partial reductions (no global atomics).
__global__ __launch_bounds__(256) void edge_reduce(const int* __restrict__ ei,
                                                   const float* __restrict__ ew,
                                                   const float* __restrict__ s,
                                                   float* __restrict__ part, int E) {
  __shared__ float loc[18];
  int tid = threadIdx.x;
  if (tid < 18) loc[tid] = 0.f;
  __syncthreads();
  bool i64 = ei_is_i64(ei);
  float dot = 0.f, w = 0.f;
  float ca[16];
#pragma unroll
  for (int k = 0; k < 16; ++k) ca[k] = 0.f;
  for (int e = blockIdx.x * 256 + tid; e < E; e += gridDim.x * 256) {
    int a = ld_idx(ei, e, i64);
    int b = ld_idx(ei, E + e, i64);
    float we = ew[e];
    const float4* sa = reinterpret_cast<const float4*>(s + (size_t)a * 16);
    const float4* sb = reinterpret_cast<const float4*>(s + (size_t)b * 16);
    float d = 0.f;
#pragma unroll
    for (int q = 0; q < 4; ++q) {
      float4 av = sa[q], bv = sb[q];
      d += av.x * bv.x + av.y * bv.y + av.z * bv.z + av.w * bv.w;
      ca[q * 4 + 0] += we * av.x; ca[q * 4 + 1] += we * av.y;
      ca[q * 4 + 2] += we * av.z; ca[q * 4 + 3] += we * av.w;
    }
    dot += we * d;
    w += we;
  }
#pragma unroll
  for (int off = 32; off; off >>= 1) {
    dot += __shfl_xor(dot, off);
    w += __shfl_xor(w, off);
#pragma unroll
    for (int k = 0; k < 16; ++k) ca[k] += __shfl_xor(ca[k], off);
  }
  if ((tid & 63) == 0) {
    atomicAdd(&loc[0], dot);
    atomicAdd(&loc[1], w);
#pragma unroll
    for (int k = 0; k < 16; ++k) atomicAdd(&loc[2 + k], ca[k]);
  }
  __syncthreads();
  if (tid < 18) part[(size_t)blockIdx.x * 18 + tid] = loc[tid];
}

__global__ __launch_bounds__(256) void finalize(const float* __restrict__ epart,
                                                const float* __restrict__ cs_part,
                                                int pool_blocks,
                                                float* __restrict__ out,
                                                int N, int s_elems) {
  __shared__ float red[18];
  __shared__ float csl[256];
  __shared__ float cs[16];
  int tid = threadIdx.x;
  if (tid < 18) {
    float a = 0.f;
    for (int b = 0; b < ER_BLOCKS; ++b) a += epart[(size_t)b * 18 + tid];
    red[tid] = a;
  }
  {
    int k = tid & 15, sl = tid >> 4;
    float a = 0.f;
    for (int b = sl; b < pool_blocks; b += 16) a += cs_part[(size_t)b * 16 + k];
    csl[tid] = a;
  }
  __syncthreads();
  if (tid < 16) {
    float a = 0.f;
#pragma unroll
    for (int sl = 0; sl < 16; ++sl) a += csl[sl * 16 + tid];
    cs[tid] = a;
  }
  __syncthreads();
  if (tid == 0) {
    float tr = red[0], m2 = red[1];
    float ca2 = 0.f, cs2 = 0.f;
    for (int k = 0; k < 16; ++k) {
      ca2 += red[2 + k] * red[2 + k];
      cs2 += cs[k] * cs[k];
    }
    float sp = -(tr - ca2 / m2) / m2;
    float cl = sqrtf(cs2) / (float)N * 4.0f - 1.0f;
    out[s_elems + 0] = 100.f * (sp + cl);
    out[s_elems + 1] = 100.f * sp;
    out[s_elems + 2] = 100.f * cl;
  }
}

extern "C" void kernel_launch(void* const* d_in, const int* in_sizes, int n_in,
                              void* d_out, int out_size, void* d_ws, size_t ws_size,
                              hipStream_t stream) {
  const float* x  = (const float*)d_in[0];
  const int*   ei = (const int*)d_in[1];
  const float* ew = (const float*)d_in[2];
  const float* W1 = (const float*)d_in[3];
  const float* b1 = (const float*)d_in[4];
  const float* W2 = (const float*)d_in[5];
  const float* b2 = (const float*)d_in[6];
  const float* Wp = (const float*)d_in[7];
  const float* bp = (const float*)d_in[8];
  float* out = (float*)d_out;

  const int IN_C = 128, HID = 256;
  const int N = in_sizes[0] / IN_C;   // 10000
  const int E = in_sizes[2];          // 160000
  const int pool_blocks = (N + 15) / 16;

  char* p = (char*)d_ws;
  auto alloc = [&](size_t b) { char* r = p; p += (b + 255) & ~(size_t)255; return r; };
  float* deg     = (float*)alloc((size_t)N * 4);
  int*   cnt     = (int*)alloc((size_t)N * 4);
  int*   cur     = (int*)alloc((size_t)N * 4);
  char*  zero_end = p;
  u16*   axhi    = (u16*)alloc((size_t)N * IN_C * 2);
  u16*   axlo    = (u16*)alloc((size_t)N * IN_C * 2);
  u16*   ahhi    = (u16*)alloc((size_t)N * HID * 2);
  u16*   ahlo    = (u16*)alloc((size_t)N * HID * 2);
  float* h       = (float*)alloc((size_t)N * HID * 4);
  float* h2      = (float*)alloc((size_t)N * HID * 4);
  u16*   w1hi    = (u16*)alloc((size_t)256 * 128 * 2);
  u16*   w1lo    = (u16*)alloc((size_t)256 * 128 * 2);
  u16*   w2hi    = (u16*)alloc((size_t)256 * 256 * 2);
  u16*   w2lo    = (u16*)alloc((size_t)256 * 256 * 2);
  int*   rowptr  = (int*)alloc((size_t)(N + 1) * 4);
  int*   col     = (int*)alloc((size_t)E * 4);
  float* coef    = (float*)alloc((size_t)E * 4);
  float* epart   = (float*)alloc((size_t)ER_BLOCKS * 18 * 4);
  float* cs_part = (float*)alloc((size_t)pool_blocks * 16 * 4);
  if ((size_t)(p - (char*)d_ws) > ws_size) return;

  int zn4 = (int)((zero_end - (char*)deg) >> 4);
  zero_init<<<(zn4 + 255) / 256, 256, 0, stream>>>((int4*)deg, zn4);
  conv_weights<<<(256 * 128 + 256 * 256 + 255) / 256, 256, 0, stream>>>(
      W1, W2, w1hi, w1lo, w2hi, w2lo);

  int eb = (E + 255) / 256;
  edge_count<<<eb, 256, 0, stream>>>(ei, ew, cnt, deg, E);
  scan_kernel<<<1, 1024, 0, stream>>>(cnt, rowptr, N);
  scatter_edges<<<eb, 256, 0, stream>>>(ei, ew, rowptr, cur, deg, col, coef, E);

  dim3 gg((N + 63) / 64, HID / 64);
  // layer 1
  aggregate_pre<128><<<N, 256, 0, stream>>>(x, rowptr, col, coef, deg, axhi, axlo, N);
  gemm_mfma<<<gg, 256, 0, stream>>>(axhi, axlo, w1hi, w1lo, b1, h, N, IN_C);
  // layer 2
  aggregate_pre<256><<<N, 256, 0, stream>>>(h, rowptr, col, coef, deg, ahhi, ahlo, N);
  gemm_mfma<<<gg, 256, 0, stream>>>(ahhi, ahlo, w2hi, w2lo, b2, h2, N, HID);

  pool_kernel<<<pool_blocks, 256, 0, stream>>>(h2, Wp, bp, out, cs_part, N);
  edge_reduce<<<ER_BLOCKS, 256, 0, stream>>>(ei, ew, out, epart, E);
  finalize<<<1, 256, 0, stream>>>(epart, cs_part, pool_blocks, out, N, N * 16);
}